// Round 1
// baseline (994.056 us; speedup 1.0000x reference)
//
#include <hip/hip_runtime.h>
#include <cstdint>
#include <cstddef>

// ---------------------------------------------------------------------------
// KAN encode: x(4096,1024) -> KANLinear(1024->2048) -> KANLinear(2048->1024)
//             -> ReLU -> Dense(1024->512)+bias
// Reformulated as bf16 MFMA GEMMs over augmented K:
//   layerL: C[b,o] = sum_{i} silu(in)[b,i]*bw[o,i] + sum_{i,k} B_k(in[b,i])*(sw*ss)[o,i,k]
//         = A_aug(b, i*9+t) @ W_aug(o, i*9+t)^T,  t=0 base, t=1..8 spline
// ---------------------------------------------------------------------------

typedef __bf16 bf16x8 __attribute__((ext_vector_type(8)));
typedef float floatx4 __attribute__((ext_vector_type(4)));

// Problem constants
#define BATCH 4096
#define DIN   1024
#define H0N   2048
#define H1N   1024
#define LOUT  512

// Workspace layout (bytes). Total = 231,735,296 (~221 MiB).
#define OFF_A0  ((size_t)0)                      // bf16 4096*9216   = 75,497,472 B
#define OFF_W0  ((size_t)75497472)               // bf16 2048*9216   = 37,748,736 B
// A1 overlays [0, 150,994,944) (A0+W0 dead by then): bf16 4096*18432
#define OFF_H0  ((size_t)150994944)              // f32 4096*2048    = 33,554,432 B
#define OFF_W1  ((size_t)(150994944 + 33554432)) // bf16 1024*18432  = 37,748,736 B
#define OFF_H1R ((size_t)(184549376 + 37748736)) // bf16 4096*1024   =  8,388,608 B
#define OFF_DW  ((size_t)(222298112 + 8388608))  // bf16 512*1024    =  1,048,576 B

// --------------------------- spline bases ----------------------------------
// Cox-de Boor, order 3, grid_size 5, knots t_j = (j-3)*0.4f - 1.0f, j=0..11.
// Matches reference fp32 knot computation; divisions replaced by compile-time
// reciprocals (exact constant folding; ulp-level difference vs reference).
__device__ __forceinline__ void bspline8(float x, float* out) {
    float b[11];
#pragma unroll
    for (int j = 0; j < 11; ++j) {
        float t0 = (j - 3) * 0.4f - 1.0f;
        float t1 = (j - 2) * 0.4f - 1.0f;
        b[j] = (x >= t0 && x < t1) ? 1.0f : 0.0f;
    }
#pragma unroll
    for (int k = 1; k <= 3; ++k) {
#pragma unroll
        for (int j = 0; j + k < 11; ++j) {
            float tj   = (j - 3) * 0.4f - 1.0f;
            float tj1  = (j - 2) * 0.4f - 1.0f;
            float tjk  = (j + k - 3) * 0.4f - 1.0f;
            float tjk1 = (j + k - 2) * 0.4f - 1.0f;
            float left  = (x - tj)   * (1.0f / (tjk - tj));
            float right = (tjk1 - x) * (1.0f / (tjk1 - tj1));
            b[j] = left * b[j] + right * b[j + 1];
        }
    }
#pragma unroll
    for (int j = 0; j < 8; ++j) out[j] = b[j];
}

// Augmented activation: in (total fp32) -> out (total*9 bf16), [silu, 8 bases]
__global__ void kan_act(const float* __restrict__ in, __bf16* __restrict__ out,
                        int total) {
    int idx = blockIdx.x * 256 + threadIdx.x;
    if (idx >= total) return;
    float v = in[idx];
    float s = v / (1.0f + __expf(-v));
    float bb[8];
    bspline8(v, bb);
    __bf16* p = out + (size_t)idx * 9;
    p[0] = (__bf16)s;
#pragma unroll
    for (int j = 0; j < 8; ++j) p[1 + j] = (__bf16)bb[j];
}

// Augmented weight: [bw[o,i], sw[o,i,k]*ss[o,i]] -> bf16 (o, i*9+t)
__global__ void kan_wprep(const float* __restrict__ bw, const float* __restrict__ sw,
                          const float* __restrict__ ss, __bf16* __restrict__ out,
                          int total) {
    int idx = blockIdx.x * 256 + threadIdx.x;
    if (idx >= total) return;
    float b  = bw[idx];
    float sc = ss[idx];
    const float4* sv = (const float4*)(sw + (size_t)idx * 8);
    float4 a = sv[0], c = sv[1];
    __bf16* p = out + (size_t)idx * 9;
    p[0] = (__bf16)b;
    p[1] = (__bf16)(a.x * sc); p[2] = (__bf16)(a.y * sc);
    p[3] = (__bf16)(a.z * sc); p[4] = (__bf16)(a.w * sc);
    p[5] = (__bf16)(c.x * sc); p[6] = (__bf16)(c.y * sc);
    p[7] = (__bf16)(c.z * sc); p[8] = (__bf16)(c.w * sc);
}

__global__ void f2bf(const float* __restrict__ in, __bf16* __restrict__ out,
                     int total) {
    int idx = blockIdx.x * 256 + threadIdx.x;
    if (idx < total) out[idx] = (__bf16)in[idx];
}

// --------------------------- MFMA GEMM -------------------------------------
// C(M,N) = A(M,K) @ W(N,K)^T, bf16 inputs, fp32 accumulate.
// 128x128 tile, BK=32, block=256 (4 waves, each 64x64 via 4x4 MFMA 16x16x32).
// EPI: 0 = store fp32; 1 = relu -> bf16; 2 = +bias[n] -> fp32.
// LDS tiles padded (+8 bf16) to break 64B-row-stride bank conflicts.
template <int EPI>
__global__ __launch_bounds__(256) void gemm_bt(
    const __bf16* __restrict__ A, const __bf16* __restrict__ W,
    void* __restrict__ Cout, const float* __restrict__ bias,
    int M, int N, int K) {
    constexpr int BM = 128, BN = 128, BK = 32, LDW = BK + 8;  // 40 elems/row
    __shared__ __bf16 As[BM * LDW];
    __shared__ __bf16 Ws[BN * LDW];

    const int tid  = threadIdx.x;
    const int lane = tid & 63;
    const int wave = tid >> 6;
    const int bm = blockIdx.y * BM;
    const int bn = blockIdx.x * BN;
    const int wm = (wave >> 1) * 64;
    const int wn = (wave & 1) * 64;
    const int lr = lane & 15;        // fragment row (m or n within 16)
    const int ks = (lane >> 4) * 8;  // fragment k offset (quad*8)

    floatx4 acc[4][4] = {};

    for (int k0 = 0; k0 < K; k0 += BK) {
        __syncthreads();  // previous iter's LDS reads must finish before overwrite
#pragma unroll
        for (int i = 0; i < 2; ++i) {
            int c = tid + i * 256;       // chunk id 0..511 (16B chunks)
            int r = c >> 2;              // tile row 0..127
            int s = (c & 3) * 8;         // k element offset 0/8/16/24
            *(float4*)&As[r * LDW + s] =
                *(const float4*)&A[(size_t)(bm + r) * K + k0 + s];
            *(float4*)&Ws[r * LDW + s] =
                *(const float4*)&W[(size_t)(bn + r) * K + k0 + s];
        }
        __syncthreads();

        bf16x8 af[4], wf[4];
#pragma unroll
        for (int t = 0; t < 4; ++t) {
            af[t] = *(const bf16x8*)&As[(wm + t * 16 + lr) * LDW + ks];
            wf[t] = *(const bf16x8*)&Ws[(wn + t * 16 + lr) * LDW + ks];
        }
#pragma unroll
        for (int mt = 0; mt < 4; ++mt)
#pragma unroll
            for (int nt = 0; nt < 4; ++nt)
                acc[mt][nt] = __builtin_amdgcn_mfma_f32_16x16x32_bf16(
                    af[mt], wf[nt], acc[mt][nt], 0, 0, 0);
    }

    // C/D layout: col = lane&15, row = (lane>>4)*4 + reg  [m89/m91 verified]
    const int col = lane & 15;
    const int rquad = (lane >> 4) * 4;
#pragma unroll
    for (int mt = 0; mt < 4; ++mt) {
#pragma unroll
        for (int nt = 0; nt < 4; ++nt) {
            int n = bn + wn + nt * 16 + col;
#pragma unroll
            for (int rg = 0; rg < 4; ++rg) {
                int m = bm + wm + mt * 16 + rquad + rg;
                float v = acc[mt][nt][rg];
                if (EPI == 0) {
                    ((float*)Cout)[(size_t)m * N + n] = v;
                } else if (EPI == 1) {
                    ((__bf16*)Cout)[(size_t)m * N + n] = (__bf16)fmaxf(v, 0.0f);
                } else {
                    ((float*)Cout)[(size_t)m * N + n] = v + bias[n];
                }
            }
        }
    }
}

// ---------------------------------------------------------------------------
extern "C" void kernel_launch(void* const* d_in, const int* in_sizes, int n_in,
                              void* d_out, int out_size, void* d_ws, size_t ws_size,
                              hipStream_t stream) {
    const float* x   = (const float*)d_in[0];
    const float* bw0 = (const float*)d_in[1];
    const float* sw0 = (const float*)d_in[2];
    const float* ss0 = (const float*)d_in[3];
    const float* bw1 = (const float*)d_in[4];
    const float* sw1 = (const float*)d_in[5];
    const float* ss1 = (const float*)d_in[6];
    const float* dw  = (const float*)d_in[7];
    const float* db  = (const float*)d_in[8];
    float* out = (float*)d_out;

    char* ws = (char*)d_ws;
    __bf16* A0  = (__bf16*)(ws + OFF_A0);
    __bf16* W0  = (__bf16*)(ws + OFF_W0);
    __bf16* A1  = (__bf16*)(ws + OFF_A0);  // overlays A0+W0 (dead by then)
    float*  h0  = (float*)(ws + OFF_H0);
    __bf16* W1  = (__bf16*)(ws + OFF_W1);
    __bf16* h1r = (__bf16*)(ws + OFF_H1R);
    __bf16* dwb = (__bf16*)(ws + OFF_DW);

    // Layer 0: augment weights + activations, GEMM (K = 1024*9 = 9216)
    kan_wprep<<<(H0N * DIN) / 256, 256, 0, stream>>>(bw0, sw0, ss0, W0, H0N * DIN);
    kan_act<<<(BATCH * DIN) / 256, 256, 0, stream>>>(x, A0, BATCH * DIN);
    gemm_bt<0><<<dim3(H0N / 128, BATCH / 128), 256, 0, stream>>>(
        A0, W0, (void*)h0, nullptr, BATCH, H0N, DIN * 9);

    // Layer 1: (K = 2048*9 = 18432), fused ReLU -> bf16 epilogue
    kan_wprep<<<(H1N * H0N) / 256, 256, 0, stream>>>(bw1, sw1, ss1, W1, H1N * H0N);
    kan_act<<<(BATCH * H0N) / 256, 256, 0, stream>>>(h0, A1, BATCH * H0N);
    gemm_bt<1><<<dim3(H1N / 128, BATCH / 128), 256, 0, stream>>>(
        A1, W1, (void*)h1r, nullptr, BATCH, H1N, H0N * 9);

    // Dense: out = relu(h1) @ dw^T + db   (K = 1024)
    f2bf<<<(LOUT * H1N) / 256, 256, 0, stream>>>(dw, dwb, LOUT * H1N);
    gemm_bt<2><<<dim3(LOUT / 128, BATCH / 128), 256, 0, stream>>>(
        h1r, dwb, (void*)out, db, BATCH, LOUT, H1N);
}

// Round 2
// 832.890 us; speedup vs baseline: 1.1935x; 1.1935x over previous
//
#include <hip/hip_runtime.h>
#include <cstdint>
#include <cstddef>

// ---------------------------------------------------------------------------
// KAN encode: x(4096,1024) -> KANLinear(1024->2048) -> KANLinear(2048->1024)
//             -> ReLU -> Dense(1024->512)+bias
// bf16 MFMA GEMMs over augmented K (9 channels per input feature).
// R2: m97-style global_load_lds staging + split-K for occupancy.
// ---------------------------------------------------------------------------

typedef __bf16 bf16x8 __attribute__((ext_vector_type(8)));
typedef float floatx4 __attribute__((ext_vector_type(4)));

#define BATCH 4096
#define DIN   1024
#define H0N   2048
#define H1N   1024
#define LOUT  512

// Workspace layout (bytes). Total = 227,540,992.
#define OFF_A0  ((size_t)0)           // bf16 4096*9216  = 75,497,472
#define OFF_W0  ((size_t)75497472)    // bf16 2048*9216  = 37,748,736
#define OFF_A1  ((size_t)0)           // bf16 4096*18432 = 150,994,944 (overlays A0+W0)
#define OFF_P0  ((size_t)150994944)   // f32 2*4096*2048 = 67,108,864
#define OFF_W1  ((size_t)218103808)   // bf16 1024*18432 = 37,748,736
#define OFF_P1  ((size_t)150994944)   // f32 4*4096*1024 = 67,108,864 (overlays P0)
#define OFF_H1R ((size_t)218103808)   // bf16 4096*1024  =  8,388,608 (overlays W1)
#define OFF_DW  ((size_t)226492416)   // bf16 512*1024   =  1,048,576

// --------------------------- spline bases ----------------------------------
__device__ __forceinline__ void bspline8(float x, float* out) {
    float b[11];
#pragma unroll
    for (int j = 0; j < 11; ++j) {
        float t0 = (j - 3) * 0.4f - 1.0f;
        float t1 = (j - 2) * 0.4f - 1.0f;
        b[j] = (x >= t0 && x < t1) ? 1.0f : 0.0f;
    }
#pragma unroll
    for (int k = 1; k <= 3; ++k) {
#pragma unroll
        for (int j = 0; j + k < 11; ++j) {
            float tj   = (j - 3) * 0.4f - 1.0f;
            float tj1  = (j - 2) * 0.4f - 1.0f;
            float tjk  = (j + k - 3) * 0.4f - 1.0f;
            float tjk1 = (j + k - 2) * 0.4f - 1.0f;
            float left  = (x - tj)   * (1.0f / (tjk - tj));
            float right = (tjk1 - x) * (1.0f / (tjk1 - tj1));
            b[j] = left * b[j] + right * b[j + 1];
        }
    }
#pragma unroll
    for (int j = 0; j < 8; ++j) out[j] = b[j];
}

__device__ __forceinline__ void write_act(__bf16* p, float v) {
    float s = v / (1.0f + __expf(-v));
    float bb[8];
    bspline8(v, bb);
    p[0] = (__bf16)s;
#pragma unroll
    for (int j = 0; j < 8; ++j) p[1 + j] = (__bf16)bb[j];
}

// in (fp32) -> out (total*9 bf16): [silu, 8 bases]
__global__ void kan_act(const float* __restrict__ in, __bf16* __restrict__ out,
                        int total) {
    int idx = blockIdx.x * 256 + threadIdx.x;
    if (idx >= total) return;
    write_act(out + (size_t)idx * 9, in[idx]);
}

// sum of 2 fp32 partials -> augmented activations
__global__ void kan_act_sum2(const float* __restrict__ pa, const float* __restrict__ pb,
                             __bf16* __restrict__ out, int total) {
    int idx = blockIdx.x * 256 + threadIdx.x;
    if (idx >= total) return;
    write_act(out + (size_t)idx * 9, pa[idx] + pb[idx]);
}

// sum 4 fp32 partials, relu, -> bf16 (4 elems/thread, vectorized)
__global__ void relu_sum4(const float* __restrict__ p, size_t stride,
                          __bf16* __restrict__ out, int total4) {
    int idx = blockIdx.x * 256 + threadIdx.x;
    if (idx >= total4) return;
    const float4* p0 = (const float4*)p;
    const float4* p1 = (const float4*)(p + stride);
    const float4* p2 = (const float4*)(p + 2 * stride);
    const float4* p3 = (const float4*)(p + 3 * stride);
    float4 a = p0[idx], b = p1[idx], c = p2[idx], d = p3[idx];
    __bf16 r[4];
    r[0] = (__bf16)fmaxf(a.x + b.x + c.x + d.x, 0.0f);
    r[1] = (__bf16)fmaxf(a.y + b.y + c.y + d.y, 0.0f);
    r[2] = (__bf16)fmaxf(a.z + b.z + c.z + d.z, 0.0f);
    r[3] = (__bf16)fmaxf(a.w + b.w + c.w + d.w, 0.0f);
    *(uint2*)&out[(size_t)idx * 4] = *(uint2*)r;
}

// Augmented weight: [bw[o,i], sw[o,i,k]*ss[o,i]] -> bf16 (o, i*9+t)
__global__ void kan_wprep(const float* __restrict__ bw, const float* __restrict__ sw,
                          const float* __restrict__ ss, __bf16* __restrict__ out,
                          int total) {
    int idx = blockIdx.x * 256 + threadIdx.x;
    if (idx >= total) return;
    float b  = bw[idx];
    float sc = ss[idx];
    const float4* sv = (const float4*)(sw + (size_t)idx * 8);
    float4 a = sv[0], c = sv[1];
    __bf16* p = out + (size_t)idx * 9;
    p[0] = (__bf16)b;
    p[1] = (__bf16)(a.x * sc); p[2] = (__bf16)(a.y * sc);
    p[3] = (__bf16)(a.z * sc); p[4] = (__bf16)(a.w * sc);
    p[5] = (__bf16)(c.x * sc); p[6] = (__bf16)(c.y * sc);
    p[7] = (__bf16)(c.z * sc); p[8] = (__bf16)(c.w * sc);
}

__global__ void f2bf(const float* __restrict__ in, __bf16* __restrict__ out,
                     int total) {
    int idx = blockIdx.x * 256 + threadIdx.x;
    if (idx < total) out[idx] = (__bf16)in[idx];
}

// --------------------------- MFMA GEMM (m97 structure) ---------------------
__device__ __forceinline__ void gload_lds16(const void* g, void* l) {
    __builtin_amdgcn_global_load_lds(
        (const __attribute__((address_space(1))) uint32_t*)g,
        (__attribute__((address_space(3))) uint32_t*)l, 16, 0, 0);
}

// C(M,N) = A(M,K) @ W(N,K)^T, bf16 in, fp32 out.
// 128x128 tile, BK=32, 256 threads (4 waves, each 64x64 = 4x4 MFMA 16x16x32).
// Split-K via blockIdx.z: block covers K rows [z*Ks, (z+1)*Ks), writes
// partial to Cout + z*M*N.  EPI: 0 = fp32 partial store, 2 = fp32 + bias[n].
template <int EPI>
__global__ __launch_bounds__(256) void gemm_bt(
    const __bf16* __restrict__ A, const __bf16* __restrict__ W,
    float* __restrict__ Cout, const float* __restrict__ bias,
    int M, int N, int K, int Ks) {
    constexpr int BK = 32;                 // LDS row = 32 bf16 = 64 B = 4 chunks
    __shared__ __bf16 As[128 * BK];        // 8 KB, unpadded (global_load_lds layout)
    __shared__ __bf16 Ws[128 * BK];        // 8 KB

    const int tid  = threadIdx.x;
    const int lane = tid & 63;
    const int wave = tid >> 6;
    const int bm = blockIdx.y * 128;
    const int bn = blockIdx.x * 128;
    const int kbase = blockIdx.z * Ks;
    const int wm = (wave >> 1) * 64;
    const int wn = (wave & 1) * 64;
    const int lr = lane & 15;
    const int ks = (lane >> 4) * 8;

    floatx4 acc[4][4] = {};

    for (int k0 = 0; k0 < Ks; k0 += BK) {
        const int kpos = kbase + k0;
        __syncthreads();   // prior iter's ds_reads done before overwrite
#pragma unroll
        for (int i = 0; i < 2; ++i) {
            int c = i * 256 + tid;       // 16B chunk id, 0..511
            int r = c >> 2;              // tile row
            int s = (c & 3) * 8;         // k-offset in elems
            // LDS dst: wave-uniform base + lane*16 (hardware-added)
            gload_lds16(&A[(size_t)(bm + r) * K + kpos + s],
                        &As[(size_t)(i * 256 + wave * 64) * 8]);
            gload_lds16(&W[(size_t)(bn + r) * K + kpos + s],
                        &Ws[(size_t)(i * 256 + wave * 64) * 8]);
        }
        __syncthreads();   // compiler emits vmcnt(0) drain before barrier

        bf16x8 af[4], wf[4];
#pragma unroll
        for (int t = 0; t < 4; ++t) {
            af[t] = *(const bf16x8*)&As[(wm + t * 16 + lr) * BK + ks];
            wf[t] = *(const bf16x8*)&Ws[(wn + t * 16 + lr) * BK + ks];
        }
#pragma unroll
        for (int mt = 0; mt < 4; ++mt)
#pragma unroll
            for (int nt = 0; nt < 4; ++nt)
                acc[mt][nt] = __builtin_amdgcn_mfma_f32_16x16x32_bf16(
                    af[mt], wf[nt], acc[mt][nt], 0, 0, 0);
    }

    // C/D layout: col = lane&15, row = (lane>>4)*4 + reg  [m89/m91]
    float* Cz = Cout + (size_t)blockIdx.z * M * N;
    const int col = lane & 15;
    const int rquad = (lane >> 4) * 4;
#pragma unroll
    for (int mt = 0; mt < 4; ++mt) {
#pragma unroll
        for (int nt = 0; nt < 4; ++nt) {
            int n = bn + wn + nt * 16 + col;
#pragma unroll
            for (int rg = 0; rg < 4; ++rg) {
                int m = bm + wm + mt * 16 + rquad + rg;
                float v = acc[mt][nt][rg];
                if (EPI == 2) v += bias[n];
                Cz[(size_t)m * N + n] = v;
            }
        }
    }
}

// ---------------------------------------------------------------------------
extern "C" void kernel_launch(void* const* d_in, const int* in_sizes, int n_in,
                              void* d_out, int out_size, void* d_ws, size_t ws_size,
                              hipStream_t stream) {
    const float* x   = (const float*)d_in[0];
    const float* bw0 = (const float*)d_in[1];
    const float* sw0 = (const float*)d_in[2];
    const float* ss0 = (const float*)d_in[3];
    const float* bw1 = (const float*)d_in[4];
    const float* sw1 = (const float*)d_in[5];
    const float* ss1 = (const float*)d_in[6];
    const float* dw  = (const float*)d_in[7];
    const float* db  = (const float*)d_in[8];
    float* out = (float*)d_out;

    char* ws = (char*)d_ws;
    __bf16* A0  = (__bf16*)(ws + OFF_A0);
    __bf16* W0  = (__bf16*)(ws + OFF_W0);
    __bf16* A1  = (__bf16*)(ws + OFF_A1);
    float*  P0  = (float*)(ws + OFF_P0);
    __bf16* W1  = (__bf16*)(ws + OFF_W1);
    float*  P1  = (float*)(ws + OFF_P1);
    __bf16* h1r = (__bf16*)(ws + OFF_H1R);
    __bf16* dwb = (__bf16*)(ws + OFF_DW);

    // Layer 0: K = 9216, splitK=2 -> grid 16x32x2 = 1024 blocks (4/CU)
    kan_wprep<<<(H0N * DIN) / 256, 256, 0, stream>>>(bw0, sw0, ss0, W0, H0N * DIN);
    kan_act<<<(BATCH * DIN) / 256, 256, 0, stream>>>(x, A0, BATCH * DIN);
    gemm_bt<0><<<dim3(H0N / 128, BATCH / 128, 2), 256, 0, stream>>>(
        A0, W0, P0, nullptr, BATCH, H0N, DIN * 9, DIN * 9 / 2);

    // Layer 1: K = 18432, splitK=4 -> grid 8x32x4 = 1024 blocks (4/CU)
    kan_wprep<<<(H1N * H0N) / 256, 256, 0, stream>>>(bw1, sw1, ss1, W1, H1N * H0N);
    kan_act_sum2<<<(BATCH * H0N) / 256, 256, 0, stream>>>(
        P0, P0 + (size_t)BATCH * H0N, A1, BATCH * H0N);
    gemm_bt<0><<<dim3(H1N / 128, BATCH / 128, 4), 256, 0, stream>>>(
        A1, W1, P1, nullptr, BATCH, H1N, H0N * 9, H0N * 9 / 4);

    // relu(sum of 4 partials) -> bf16
    relu_sum4<<<(BATCH * H1N / 4) / 256, 256, 0, stream>>>(
        P1, (size_t)BATCH * H1N, h1r, BATCH * H1N / 4);

    // Dense: out = h1r @ dw^T + db  (K = 1024), unsplit (tiny)
    f2bf<<<(LOUT * H1N) / 256, 256, 0, stream>>>(dw, dwb, LOUT * H1N);
    gemm_bt<2><<<dim3(LOUT / 128, BATCH / 128, 1), 256, 0, stream>>>(
        h1r, dwb, out, db, BATCH, LOUT, H1N, H1N);
}

// Round 3
// 775.321 us; speedup vs baseline: 1.2821x; 1.0743x over previous
//
#include <hip/hip_runtime.h>
#include <cstdint>
#include <cstddef>

// ---------------------------------------------------------------------------
// KAN encode: x(4096,1024) -> KANLinear(1024->2048) -> KANLinear(2048->1024)
//             -> ReLU -> Dense(1024->512)+bias
// bf16 MFMA GEMMs over augmented K (9 channels per input feature).
// R3: double-buffered LDS prefetch (stage k+1 before compute k) to hide
//     LLC/HBM latency behind the vmcnt(0) barrier drain; LDS-coalesced
//     stores in act/wprep kernels.
// ---------------------------------------------------------------------------

typedef __bf16 bf16x8 __attribute__((ext_vector_type(8)));
typedef float floatx4 __attribute__((ext_vector_type(4)));

#define BATCH 4096
#define DIN   1024
#define H0N   2048
#define H1N   1024
#define LOUT  512

// Workspace layout (bytes). Total = 227,540,992 (known to fit).
#define OFF_A0  ((size_t)0)           // bf16 4096*9216  = 75,497,472
#define OFF_W0  ((size_t)75497472)    // bf16 2048*9216  = 37,748,736
#define OFF_A1  ((size_t)0)           // bf16 4096*18432 = 150,994,944 (overlays A0+W0)
#define OFF_P0  ((size_t)150994944)   // f32 2*4096*2048 = 67,108,864
#define OFF_W1  ((size_t)218103808)   // bf16 1024*18432 = 37,748,736
#define OFF_P1  ((size_t)150994944)   // f32 4*4096*1024 = 67,108,864 (overlays P0)
#define OFF_H1R ((size_t)218103808)   // bf16 4096*1024  =  8,388,608 (overlays W1)
#define OFF_DW  ((size_t)226492416)   // bf16 512*1024   =  1,048,576

// --------------------------- spline bases ----------------------------------
__device__ __forceinline__ void bspline8(float x, float* out) {
    float b[11];
#pragma unroll
    for (int j = 0; j < 11; ++j) {
        float t0 = (j - 3) * 0.4f - 1.0f;
        float t1 = (j - 2) * 0.4f - 1.0f;
        b[j] = (x >= t0 && x < t1) ? 1.0f : 0.0f;
    }
#pragma unroll
    for (int k = 1; k <= 3; ++k) {
#pragma unroll
        for (int j = 0; j + k < 11; ++j) {
            float tj   = (j - 3) * 0.4f - 1.0f;
            float tj1  = (j - 2) * 0.4f - 1.0f;
            float tjk  = (j + k - 3) * 0.4f - 1.0f;
            float tjk1 = (j + k - 2) * 0.4f - 1.0f;
            float left  = (x - tj)   * (1.0f / (tjk - tj));
            float right = (tjk1 - x) * (1.0f / (tjk1 - tj1));
            b[j] = left * b[j] + right * b[j + 1];
        }
    }
#pragma unroll
    for (int j = 0; j < 8; ++j) out[j] = b[j];
}

// Store 256 threads * 9 bf16 via LDS as 288 coalesced 16B chunks.
__device__ __forceinline__ void coalesced_store9(__bf16* block_dst, const __bf16* vals) {
    __shared__ __bf16 sbuf[256 * 9];
    __bf16* p = &sbuf[threadIdx.x * 9];
#pragma unroll
    for (int j = 0; j < 9; ++j) p[j] = vals[j];
    __syncthreads();
    const uint4* src = (const uint4*)sbuf;
    uint4* dst = (uint4*)block_dst;
    dst[threadIdx.x] = src[threadIdx.x];
    if (threadIdx.x < 32) dst[256 + threadIdx.x] = src[256 + threadIdx.x];
}

__device__ __forceinline__ void act9(float v, __bf16* r) {
    float s = v / (1.0f + __expf(-v));
    float bb[8];
    bspline8(v, bb);
    r[0] = (__bf16)s;
#pragma unroll
    for (int j = 0; j < 8; ++j) r[1 + j] = (__bf16)bb[j];
}

// in (fp32) -> out (total*9 bf16): [silu, 8 bases]
__global__ void kan_act(const float* __restrict__ in, __bf16* __restrict__ out) {
    int base = blockIdx.x * 256;
    float v = in[base + threadIdx.x];
    __bf16 r[9];
    act9(v, r);
    coalesced_store9(out + (size_t)base * 9, r);
}

// sum of 2 fp32 partials -> augmented activations
__global__ void kan_act_sum2(const float* __restrict__ pa, const float* __restrict__ pb,
                             __bf16* __restrict__ out) {
    int base = blockIdx.x * 256;
    int idx = base + threadIdx.x;
    float v = pa[idx] + pb[idx];
    __bf16 r[9];
    act9(v, r);
    coalesced_store9(out + (size_t)base * 9, r);
}

// sum 4 fp32 partials, relu, -> bf16 (4 elems/thread, vectorized)
__global__ void relu_sum4(const float* __restrict__ p, size_t stride,
                          __bf16* __restrict__ out, int total4) {
    int idx = blockIdx.x * 256 + threadIdx.x;
    if (idx >= total4) return;
    const float4* p0 = (const float4*)p;
    const float4* p1 = (const float4*)(p + stride);
    const float4* p2 = (const float4*)(p + 2 * stride);
    const float4* p3 = (const float4*)(p + 3 * stride);
    float4 a = p0[idx], b = p1[idx], c = p2[idx], d = p3[idx];
    __bf16 r[4];
    r[0] = (__bf16)fmaxf(a.x + b.x + c.x + d.x, 0.0f);
    r[1] = (__bf16)fmaxf(a.y + b.y + c.y + d.y, 0.0f);
    r[2] = (__bf16)fmaxf(a.z + b.z + c.z + d.z, 0.0f);
    r[3] = (__bf16)fmaxf(a.w + b.w + c.w + d.w, 0.0f);
    *(uint2*)&out[(size_t)idx * 4] = *(uint2*)r;
}

// Augmented weight: [bw[o,i], sw[o,i,k]*ss[o,i]] -> bf16 (o, i*9+t)
__global__ void kan_wprep(const float* __restrict__ bw, const float* __restrict__ sw,
                          const float* __restrict__ ss, __bf16* __restrict__ out) {
    int base = blockIdx.x * 256;
    int idx = base + threadIdx.x;
    float b  = bw[idx];
    float sc = ss[idx];
    const float4* sv = (const float4*)(sw + (size_t)idx * 8);
    float4 a = sv[0], c = sv[1];
    __bf16 r[9];
    r[0] = (__bf16)b;
    r[1] = (__bf16)(a.x * sc); r[2] = (__bf16)(a.y * sc);
    r[3] = (__bf16)(a.z * sc); r[4] = (__bf16)(a.w * sc);
    r[5] = (__bf16)(c.x * sc); r[6] = (__bf16)(c.y * sc);
    r[7] = (__bf16)(c.z * sc); r[8] = (__bf16)(c.w * sc);
    coalesced_store9(out + (size_t)base * 9, r);
}

__global__ void f2bf(const float* __restrict__ in, __bf16* __restrict__ out,
                     int total) {
    int idx = blockIdx.x * 256 + threadIdx.x;
    if (idx < total) out[idx] = (__bf16)in[idx];
}

// --------------------------- MFMA GEMM (dbuf prefetch) ---------------------
__device__ __forceinline__ void gload_lds16(const void* g, void* l) {
    __builtin_amdgcn_global_load_lds(
        (const __attribute__((address_space(1))) uint32_t*)g,
        (__attribute__((address_space(3))) uint32_t*)l, 16, 0, 0);
}

// C(M,N) = A(M,K) @ W(N,K)^T, bf16 in, fp32 out.
// 128x128 tile, BK=32, 256 threads (4 waves, each 64x64 = 4x4 MFMA 16x16x32).
// Double-buffered LDS: staging for step k+1 is issued before compute of
// step k, so the compiler's vmcnt(0)-before-barrier drain waits on loads
// that already had a full compute phase of flight time.
// Requires Ks % 64 == 0. Split-K via blockIdx.z (partial -> Cout + z*M*N).
// EPI: 0 = fp32 partial store, 2 = fp32 + bias[n].
template <int EPI>
__global__ __launch_bounds__(256) void gemm_bt(
    const __bf16* __restrict__ A, const __bf16* __restrict__ W,
    float* __restrict__ Cout, const float* __restrict__ bias,
    int M, int N, int K, int Ks) {
    constexpr int BK = 32;                   // LDS row = 32 bf16 = 64 B
    __shared__ __bf16 As[2][128 * BK];       // 2 x 8 KB
    __shared__ __bf16 Ws[2][128 * BK];       // 2 x 8 KB

    const int tid  = threadIdx.x;
    const int lane = tid & 63;
    const int wave = tid >> 6;
    const int bm = blockIdx.y * 128;
    const int bn = blockIdx.x * 128;
    const int kbase = blockIdx.z * Ks;
    const int wm = (wave >> 1) * 64;
    const int wn = (wave & 1) * 64;
    const int lr = lane & 15;
    const int ks = (lane >> 4) * 8;

    floatx4 acc[4][4] = {};

    // Stage one BK-tile into buffer `buf` at K-offset kbase+kpos.
    auto stage = [&](int buf, int kpos) {
#pragma unroll
        for (int i = 0; i < 2; ++i) {
            int c = i * 256 + tid;       // 16B chunk id 0..511
            int r = c >> 2;              // tile row
            int s = (c & 3) * 8;         // k elem offset
            gload_lds16(&A[(size_t)(bm + r) * K + kbase + kpos + s],
                        &As[buf][(size_t)(i * 256 + wave * 64) * 8]);
            gload_lds16(&W[(size_t)(bn + r) * K + kbase + kpos + s],
                        &Ws[buf][(size_t)(i * 256 + wave * 64) * 8]);
        }
    };

    auto compute = [&](int buf) {
        bf16x8 af[4], wf[4];
#pragma unroll
        for (int t = 0; t < 4; ++t) {
            af[t] = *(const bf16x8*)&As[buf][(wm + t * 16 + lr) * BK + ks];
            wf[t] = *(const bf16x8*)&Ws[buf][(wn + t * 16 + lr) * BK + ks];
        }
#pragma unroll
        for (int mt = 0; mt < 4; ++mt)
#pragma unroll
            for (int nt = 0; nt < 4; ++nt)
                acc[mt][nt] = __builtin_amdgcn_mfma_f32_16x16x32_bf16(
                    af[mt], wf[nt], acc[mt][nt], 0, 0, 0);
    };

    stage(0, 0);
    for (int k0 = 0; k0 < Ks; k0 += 2 * BK) {
        __syncthreads();                       // drains stage(buf0, k0)
        if (k0 + BK < Ks) stage(1, k0 + BK);   // prefetch next tile
        compute(0);
        __syncthreads();                       // drains stage(buf1, k0+BK)
        if (k0 + 2 * BK < Ks) stage(0, k0 + 2 * BK);
        compute(1);
    }

    // C/D layout: col = lane&15, row = (lane>>4)*4 + reg  [m89/m91]
    float* Cz = Cout + (size_t)blockIdx.z * M * N;
    const int col = lane & 15;
    const int rquad = (lane >> 4) * 4;
#pragma unroll
    for (int mt = 0; mt < 4; ++mt) {
#pragma unroll
        for (int nt = 0; nt < 4; ++nt) {
            int n = bn + wn + nt * 16 + col;
#pragma unroll
            for (int rg = 0; rg < 4; ++rg) {
                int m = bm + wm + mt * 16 + rquad + rg;
                float v = acc[mt][nt][rg];
                if (EPI == 2) v += bias[n];
                Cz[(size_t)m * N + n] = v;
            }
        }
    }
}

// ---------------------------------------------------------------------------
extern "C" void kernel_launch(void* const* d_in, const int* in_sizes, int n_in,
                              void* d_out, int out_size, void* d_ws, size_t ws_size,
                              hipStream_t stream) {
    const float* x   = (const float*)d_in[0];
    const float* bw0 = (const float*)d_in[1];
    const float* sw0 = (const float*)d_in[2];
    const float* ss0 = (const float*)d_in[3];
    const float* bw1 = (const float*)d_in[4];
    const float* sw1 = (const float*)d_in[5];
    const float* ss1 = (const float*)d_in[6];
    const float* dw  = (const float*)d_in[7];
    const float* db  = (const float*)d_in[8];
    float* out = (float*)d_out;

    char* ws = (char*)d_ws;
    __bf16* A0  = (__bf16*)(ws + OFF_A0);
    __bf16* W0  = (__bf16*)(ws + OFF_W0);
    __bf16* A1  = (__bf16*)(ws + OFF_A1);
    float*  P0  = (float*)(ws + OFF_P0);
    __bf16* W1  = (__bf16*)(ws + OFF_W1);
    float*  P1  = (float*)(ws + OFF_P1);
    __bf16* h1r = (__bf16*)(ws + OFF_H1R);
    __bf16* dwb = (__bf16*)(ws + OFF_DW);

    // Layer 0: K = 9216, splitK=2 -> grid 16x32x2 = 1024 blocks
    kan_wprep<<<(H0N * DIN) / 256, 256, 0, stream>>>(bw0, sw0, ss0, W0);
    kan_act<<<(BATCH * DIN) / 256, 256, 0, stream>>>(x, A0);
    gemm_bt<0><<<dim3(H0N / 128, BATCH / 128, 2), 256, 0, stream>>>(
        A0, W0, P0, nullptr, BATCH, H0N, DIN * 9, DIN * 9 / 2);

    // Layer 1: K = 18432, splitK=4 -> grid 8x32x4 = 1024 blocks
    kan_wprep<<<(H1N * H0N) / 256, 256, 0, stream>>>(bw1, sw1, ss1, W1);
    kan_act_sum2<<<(BATCH * H0N) / 256, 256, 0, stream>>>(
        P0, P0 + (size_t)BATCH * H0N, A1);
    gemm_bt<0><<<dim3(H1N / 128, BATCH / 128, 4), 256, 0, stream>>>(
        A1, W1, P1, nullptr, BATCH, H1N, H0N * 9, H0N * 9 / 4);

    // relu(sum of 4 partials) -> bf16
    relu_sum4<<<(BATCH * H1N / 4) / 256, 256, 0, stream>>>(
        P1, (size_t)BATCH * H1N, h1r, BATCH * H1N / 4);

    // Dense: out = h1r @ dw^T + db  (K = 1024), unsplit (tiny)
    f2bf<<<(LOUT * H1N) / 256, 256, 0, stream>>>(dw, dwb, LOUT * H1N);
    gemm_bt<2><<<dim3(LOUT / 128, BATCH / 128, 1), 256, 0, stream>>>(
        h1r, dwb, out, db, BATCH, LOUT, H1N, H1N);
}

// Round 4
// 751.012 us; speedup vs baseline: 1.3236x; 1.0324x over previous
//
#include <hip/hip_runtime.h>
#include <cstdint>
#include <cstddef>

// ---------------------------------------------------------------------------
// KAN encode: x(4096,1024) -> KANLinear(1024->2048) -> KANLinear(2048->1024)
//             -> ReLU -> Dense(1024->512)+bias
// bf16 MFMA GEMMs over augmented K (9 channels per input feature).
// R4: XCD-aware block swizzle — each XCD owns an m-slab so its private L2
//     serves the staging window (A was being re-fetched 8x through LLC).
//     Keeps R3's dbuf global_load_lds staging.
// ---------------------------------------------------------------------------

typedef __bf16 bf16x8 __attribute__((ext_vector_type(8)));
typedef float floatx4 __attribute__((ext_vector_type(4)));

#define BATCH 4096
#define DIN   1024
#define H0N   2048
#define H1N   1024
#define LOUT  512

// Workspace layout (bytes). Total = 227,540,992.
#define OFF_A0  ((size_t)0)           // bf16 4096*9216  = 75,497,472
#define OFF_W0  ((size_t)75497472)    // bf16 2048*9216  = 37,748,736
#define OFF_A1  ((size_t)0)           // bf16 4096*18432 = 150,994,944 (overlays A0+W0)
#define OFF_P0  ((size_t)150994944)   // f32 2*4096*2048 = 67,108,864
#define OFF_W1  ((size_t)218103808)   // bf16 1024*18432 = 37,748,736
#define OFF_P1  ((size_t)150994944)   // f32 4*4096*1024 = 67,108,864 (overlays P0)
#define OFF_H1R ((size_t)218103808)   // bf16 4096*1024  =  8,388,608 (overlays W1)
#define OFF_DW  ((size_t)226492416)   // bf16 512*1024   =  1,048,576

// --------------------------- spline bases ----------------------------------
__device__ __forceinline__ void bspline8(float x, float* out) {
    float b[11];
#pragma unroll
    for (int j = 0; j < 11; ++j) {
        float t0 = (j - 3) * 0.4f - 1.0f;
        float t1 = (j - 2) * 0.4f - 1.0f;
        b[j] = (x >= t0 && x < t1) ? 1.0f : 0.0f;
    }
#pragma unroll
    for (int k = 1; k <= 3; ++k) {
#pragma unroll
        for (int j = 0; j + k < 11; ++j) {
            float tj   = (j - 3) * 0.4f - 1.0f;
            float tj1  = (j - 2) * 0.4f - 1.0f;
            float tjk  = (j + k - 3) * 0.4f - 1.0f;
            float tjk1 = (j + k - 2) * 0.4f - 1.0f;
            float left  = (x - tj)   * (1.0f / (tjk - tj));
            float right = (tjk1 - x) * (1.0f / (tjk1 - tj1));
            b[j] = left * b[j] + right * b[j + 1];
        }
    }
#pragma unroll
    for (int j = 0; j < 8; ++j) out[j] = b[j];
}

// Store 256 threads * 9 bf16 via LDS as 288 coalesced 16B chunks.
__device__ __forceinline__ void coalesced_store9(__bf16* block_dst, const __bf16* vals) {
    __shared__ __bf16 sbuf[256 * 9];
    __bf16* p = &sbuf[threadIdx.x * 9];
#pragma unroll
    for (int j = 0; j < 9; ++j) p[j] = vals[j];
    __syncthreads();
    const uint4* src = (const uint4*)sbuf;
    uint4* dst = (uint4*)block_dst;
    dst[threadIdx.x] = src[threadIdx.x];
    if (threadIdx.x < 32) dst[256 + threadIdx.x] = src[256 + threadIdx.x];
}

__device__ __forceinline__ void act9(float v, __bf16* r) {
    float s = v / (1.0f + __expf(-v));
    float bb[8];
    bspline8(v, bb);
    r[0] = (__bf16)s;
#pragma unroll
    for (int j = 0; j < 8; ++j) r[1 + j] = (__bf16)bb[j];
}

__global__ void kan_act(const float* __restrict__ in, __bf16* __restrict__ out) {
    int base = blockIdx.x * 256;
    float v = in[base + threadIdx.x];
    __bf16 r[9];
    act9(v, r);
    coalesced_store9(out + (size_t)base * 9, r);
}

__global__ void kan_act_sum2(const float* __restrict__ pa, const float* __restrict__ pb,
                             __bf16* __restrict__ out) {
    int base = blockIdx.x * 256;
    int idx = base + threadIdx.x;
    float v = pa[idx] + pb[idx];
    __bf16 r[9];
    act9(v, r);
    coalesced_store9(out + (size_t)base * 9, r);
}

__global__ void relu_sum4(const float* __restrict__ p, size_t stride,
                          __bf16* __restrict__ out, int total4) {
    int idx = blockIdx.x * 256 + threadIdx.x;
    if (idx >= total4) return;
    const float4* p0 = (const float4*)p;
    const float4* p1 = (const float4*)(p + stride);
    const float4* p2 = (const float4*)(p + 2 * stride);
    const float4* p3 = (const float4*)(p + 3 * stride);
    float4 a = p0[idx], b = p1[idx], c = p2[idx], d = p3[idx];
    __bf16 r[4];
    r[0] = (__bf16)fmaxf(a.x + b.x + c.x + d.x, 0.0f);
    r[1] = (__bf16)fmaxf(a.y + b.y + c.y + d.y, 0.0f);
    r[2] = (__bf16)fmaxf(a.z + b.z + c.z + d.z, 0.0f);
    r[3] = (__bf16)fmaxf(a.w + b.w + c.w + d.w, 0.0f);
    *(uint2*)&out[(size_t)idx * 4] = *(uint2*)r;
}

__global__ void kan_wprep(const float* __restrict__ bw, const float* __restrict__ sw,
                          const float* __restrict__ ss, __bf16* __restrict__ out) {
    int base = blockIdx.x * 256;
    int idx = base + threadIdx.x;
    float b  = bw[idx];
    float sc = ss[idx];
    const float4* sv = (const float4*)(sw + (size_t)idx * 8);
    float4 a = sv[0], c = sv[1];
    __bf16 r[9];
    r[0] = (__bf16)b;
    r[1] = (__bf16)(a.x * sc); r[2] = (__bf16)(a.y * sc);
    r[3] = (__bf16)(a.z * sc); r[4] = (__bf16)(a.w * sc);
    r[5] = (__bf16)(c.x * sc); r[6] = (__bf16)(c.y * sc);
    r[7] = (__bf16)(c.z * sc); r[8] = (__bf16)(c.w * sc);
    coalesced_store9(out + (size_t)base * 9, r);
}

__global__ void f2bf(const float* __restrict__ in, __bf16* __restrict__ out,
                     int total) {
    int idx = blockIdx.x * 256 + threadIdx.x;
    if (idx < total) out[idx] = (__bf16)in[idx];
}

// --------------------------- MFMA GEMM -------------------------------------
__device__ __forceinline__ void gload_lds16(const void* g, void* l) {
    __builtin_amdgcn_global_load_lds(
        (const __attribute__((address_space(1))) uint32_t*)g,
        (__attribute__((address_space(3))) uint32_t*)l, 16, 0, 0);
}

// C(M,N) = A(M,K) @ W(N,K)^T, bf16 in, fp32 out.
// 128x128 tile, BK=32, 256 threads (4 waves, each 64x64 = 4x4 MFMA 16x16x32).
// Double-buffered LDS via global_load_lds; XCD-aware swizzle: linear block id
// i -> XCD (i&7) [round-robin dispatch]; each XCD owns a contiguous m-slab
// (gridDim.y/8 m-tiles) x all n x all z, so the XCD's resident staging
// window (~400 KB) lives in its 4 MB L2 instead of thrashing LLC.
// Requires gridDim.y % 8 == 0, Ks % 64 == 0.
// EPI: 0 = fp32 partial store (Cout + z*M*N), 2 = fp32 + bias[n].
template <int EPI>
__global__ __launch_bounds__(256) void gemm_bt(
    const __bf16* __restrict__ A, const __bf16* __restrict__ W,
    float* __restrict__ Cout, const float* __restrict__ bias,
    int M, int N, int K, int Ks) {
    constexpr int BK = 32;                   // LDS row = 32 bf16 = 64 B
    __shared__ __bf16 As[2][128 * BK];       // 2 x 8 KB
    __shared__ __bf16 Ws[2][128 * BK];       // 2 x 8 KB

    const int tid  = threadIdx.x;
    const int lane = tid & 63;
    const int wave = tid >> 6;

    // ---- XCD-aware swizzle ----
    const int id    = (blockIdx.z * gridDim.y + blockIdx.y) * gridDim.x + blockIdx.x;
    const int mslab = gridDim.y >> 3;        // m-tiles per XCD
    const int xcd   = id & 7;
    const int local = id >> 3;
    const int m_off = local % mslab;
    const int rest  = local / mslab;
    const int nt    = rest % gridDim.x;
    const int zt    = rest / gridDim.x;
    const int bm    = (xcd * mslab + m_off) * 128;
    const int bn    = nt * 128;
    const int kbase = zt * Ks;

    const int wm = (wave >> 1) * 64;
    const int wn = (wave & 1) * 64;
    const int lr = lane & 15;
    const int ks = (lane >> 4) * 8;

    floatx4 acc[4][4] = {};

    auto stage = [&](int buf, int kpos) {
#pragma unroll
        for (int i = 0; i < 2; ++i) {
            int c = i * 256 + tid;       // 16B chunk id 0..511
            int r = c >> 2;              // tile row
            int s = (c & 3) * 8;         // k elem offset
            gload_lds16(&A[(size_t)(bm + r) * K + kbase + kpos + s],
                        &As[buf][(size_t)(i * 256 + wave * 64) * 8]);
            gload_lds16(&W[(size_t)(bn + r) * K + kbase + kpos + s],
                        &Ws[buf][(size_t)(i * 256 + wave * 64) * 8]);
        }
    };

    auto compute = [&](int buf) {
        bf16x8 af[4], wf[4];
#pragma unroll
        for (int t = 0; t < 4; ++t) {
            af[t] = *(const bf16x8*)&As[buf][(wm + t * 16 + lr) * BK + ks];
            wf[t] = *(const bf16x8*)&Ws[buf][(wn + t * 16 + lr) * BK + ks];
        }
#pragma unroll
        for (int mt = 0; mt < 4; ++mt)
#pragma unroll
            for (int nt2 = 0; nt2 < 4; ++nt2)
                acc[mt][nt2] = __builtin_amdgcn_mfma_f32_16x16x32_bf16(
                    af[mt], wf[nt2], acc[mt][nt2], 0, 0, 0);
    };

    stage(0, 0);
    for (int k0 = 0; k0 < Ks; k0 += 2 * BK) {
        __syncthreads();                       // drains stage(buf0, k0)
        if (k0 + BK < Ks) stage(1, k0 + BK);   // prefetch next tile
        compute(0);
        __syncthreads();                       // drains stage(buf1, k0+BK)
        if (k0 + 2 * BK < Ks) stage(0, k0 + 2 * BK);
        compute(1);
    }

    // C/D layout: col = lane&15, row = (lane>>4)*4 + reg  [m89/m91]
    float* Cz = Cout + (size_t)zt * M * N;
    const int col = lane & 15;
    const int rquad = (lane >> 4) * 4;
#pragma unroll
    for (int mt = 0; mt < 4; ++mt) {
#pragma unroll
        for (int nt2 = 0; nt2 < 4; ++nt2) {
            int n = bn + wn + nt2 * 16 + col;
#pragma unroll
            for (int rg = 0; rg < 4; ++rg) {
                int m = bm + wm + mt * 16 + rquad + rg;
                float v = acc[mt][nt2][rg];
                if (EPI == 2) v += bias[n];
                Cz[(size_t)m * N + n] = v;
            }
        }
    }
}

// ---------------------------------------------------------------------------
extern "C" void kernel_launch(void* const* d_in, const int* in_sizes, int n_in,
                              void* d_out, int out_size, void* d_ws, size_t ws_size,
                              hipStream_t stream) {
    const float* x   = (const float*)d_in[0];
    const float* bw0 = (const float*)d_in[1];
    const float* sw0 = (const float*)d_in[2];
    const float* ss0 = (const float*)d_in[3];
    const float* bw1 = (const float*)d_in[4];
    const float* sw1 = (const float*)d_in[5];
    const float* ss1 = (const float*)d_in[6];
    const float* dw  = (const float*)d_in[7];
    const float* db  = (const float*)d_in[8];
    float* out = (float*)d_out;

    char* ws = (char*)d_ws;
    __bf16* A0  = (__bf16*)(ws + OFF_A0);
    __bf16* W0  = (__bf16*)(ws + OFF_W0);
    __bf16* A1  = (__bf16*)(ws + OFF_A1);
    float*  P0  = (float*)(ws + OFF_P0);
    __bf16* W1  = (__bf16*)(ws + OFF_W1);
    float*  P1  = (float*)(ws + OFF_P1);
    __bf16* h1r = (__bf16*)(ws + OFF_H1R);
    __bf16* dwb = (__bf16*)(ws + OFF_DW);

    // Layer 0: K = 9216, splitK=2 -> grid 16x32x2 = 1024 blocks
    kan_wprep<<<(H0N * DIN) / 256, 256, 0, stream>>>(bw0, sw0, ss0, W0);
    kan_act<<<(BATCH * DIN) / 256, 256, 0, stream>>>(x, A0);
    gemm_bt<0><<<dim3(H0N / 128, BATCH / 128, 2), 256, 0, stream>>>(
        A0, W0, P0, nullptr, BATCH, H0N, DIN * 9, DIN * 9 / 2);

    // Layer 1: K = 18432, splitK=4 -> grid 8x32x4 = 1024 blocks
    kan_wprep<<<(H1N * H0N) / 256, 256, 0, stream>>>(bw1, sw1, ss1, W1);
    kan_act_sum2<<<(BATCH * H0N) / 256, 256, 0, stream>>>(
        P0, P0 + (size_t)BATCH * H0N, A1);
    gemm_bt<0><<<dim3(H1N / 128, BATCH / 128, 4), 256, 0, stream>>>(
        A1, W1, P1, nullptr, BATCH, H1N, H0N * 9, H0N * 9 / 4);

    // relu(sum of 4 partials) -> bf16
    relu_sum4<<<(BATCH * H1N / 4) / 256, 256, 0, stream>>>(
        P1, (size_t)BATCH * H1N, h1r, BATCH * H1N / 4);

    // Dense: out = h1r @ dw^T + db  (K = 1024)
    f2bf<<<(LOUT * H1N) / 256, 256, 0, stream>>>(dw, dwb, LOUT * H1N);
    gemm_bt<2><<<dim3(LOUT / 128, BATCH / 128, 1), 256, 0, stream>>>(
        h1r, dwb, out, db, BATCH, LOUT, H1N, H1N);
}

// Round 5
// 621.645 us; speedup vs baseline: 1.5991x; 1.2081x over previous
//
#include <hip/hip_runtime.h>
#include <cstdint>
#include <cstddef>

// ---------------------------------------------------------------------------
// KAN encode: x(4096,1024) -> KANLinear(1024->2048) -> KANLinear(2048->1024)
//             -> ReLU -> Dense(1024->512)+bias
// bf16 MFMA GEMMs over augmented K (9 channels per input feature).
// R5: 256x128 block tile (wave = 64m x 128n) for the two KAN GEMMs —
//     2x arithmetic intensity per barrier (longer load flight time, fewer
//     LDS bytes/MFMA, half the W fetch). Keeps dbuf global_load_lds + XCD
//     m-slab swizzle. Dense layer keeps the 128x128 kernel.
// ---------------------------------------------------------------------------

typedef __bf16 bf16x8 __attribute__((ext_vector_type(8)));
typedef float floatx4 __attribute__((ext_vector_type(4)));

#define BATCH 4096
#define DIN   1024
#define H0N   2048
#define H1N   1024
#define LOUT  512

// Workspace layout (bytes). Total = 227,540,992.
#define OFF_A0  ((size_t)0)           // bf16 4096*9216  = 75,497,472
#define OFF_W0  ((size_t)75497472)    // bf16 2048*9216  = 37,748,736
#define OFF_A1  ((size_t)0)           // bf16 4096*18432 = 150,994,944 (overlays A0+W0)
#define OFF_P0  ((size_t)150994944)   // f32 2*4096*2048 = 67,108,864
#define OFF_W1  ((size_t)218103808)   // bf16 1024*18432 = 37,748,736
#define OFF_P1  ((size_t)150994944)   // f32 4*4096*1024 = 67,108,864 (overlays P0)
#define OFF_H1R ((size_t)218103808)   // bf16 4096*1024  =  8,388,608 (overlays W1)
#define OFF_DW  ((size_t)226492416)   // bf16 512*1024   =  1,048,576

// --------------------------- spline bases ----------------------------------
__device__ __forceinline__ void bspline8(float x, float* out) {
    float b[11];
#pragma unroll
    for (int j = 0; j < 11; ++j) {
        float t0 = (j - 3) * 0.4f - 1.0f;
        float t1 = (j - 2) * 0.4f - 1.0f;
        b[j] = (x >= t0 && x < t1) ? 1.0f : 0.0f;
    }
#pragma unroll
    for (int k = 1; k <= 3; ++k) {
#pragma unroll
        for (int j = 0; j + k < 11; ++j) {
            float tj   = (j - 3) * 0.4f - 1.0f;
            float tj1  = (j - 2) * 0.4f - 1.0f;
            float tjk  = (j + k - 3) * 0.4f - 1.0f;
            float tjk1 = (j + k - 2) * 0.4f - 1.0f;
            float left  = (x - tj)   * (1.0f / (tjk - tj));
            float right = (tjk1 - x) * (1.0f / (tjk1 - tj1));
            b[j] = left * b[j] + right * b[j + 1];
        }
    }
#pragma unroll
    for (int j = 0; j < 8; ++j) out[j] = b[j];
}

// Store 256 threads * 9 bf16 via LDS as 288 coalesced 16B chunks.
__device__ __forceinline__ void coalesced_store9(__bf16* block_dst, const __bf16* vals) {
    __shared__ __bf16 sbuf[256 * 9];
    __bf16* p = &sbuf[threadIdx.x * 9];
#pragma unroll
    for (int j = 0; j < 9; ++j) p[j] = vals[j];
    __syncthreads();
    const uint4* src = (const uint4*)sbuf;
    uint4* dst = (uint4*)block_dst;
    dst[threadIdx.x] = src[threadIdx.x];
    if (threadIdx.x < 32) dst[256 + threadIdx.x] = src[256 + threadIdx.x];
}

__device__ __forceinline__ void act9(float v, __bf16* r) {
    float s = v / (1.0f + __expf(-v));
    float bb[8];
    bspline8(v, bb);
    r[0] = (__bf16)s;
#pragma unroll
    for (int j = 0; j < 8; ++j) r[1 + j] = (__bf16)bb[j];
}

__global__ void kan_act(const float* __restrict__ in, __bf16* __restrict__ out) {
    int base = blockIdx.x * 256;
    float v = in[base + threadIdx.x];
    __bf16 r[9];
    act9(v, r);
    coalesced_store9(out + (size_t)base * 9, r);
}

__global__ void kan_act_sum2(const float* __restrict__ pa, const float* __restrict__ pb,
                             __bf16* __restrict__ out) {
    int base = blockIdx.x * 256;
    int idx = base + threadIdx.x;
    float v = pa[idx] + pb[idx];
    __bf16 r[9];
    act9(v, r);
    coalesced_store9(out + (size_t)base * 9, r);
}

__global__ void relu_sum4(const float* __restrict__ p, size_t stride,
                          __bf16* __restrict__ out, int total4) {
    int idx = blockIdx.x * 256 + threadIdx.x;
    if (idx >= total4) return;
    const float4* p0 = (const float4*)p;
    const float4* p1 = (const float4*)(p + stride);
    const float4* p2 = (const float4*)(p + 2 * stride);
    const float4* p3 = (const float4*)(p + 3 * stride);
    float4 a = p0[idx], b = p1[idx], c = p2[idx], d = p3[idx];
    __bf16 r[4];
    r[0] = (__bf16)fmaxf(a.x + b.x + c.x + d.x, 0.0f);
    r[1] = (__bf16)fmaxf(a.y + b.y + c.y + d.y, 0.0f);
    r[2] = (__bf16)fmaxf(a.z + b.z + c.z + d.z, 0.0f);
    r[3] = (__bf16)fmaxf(a.w + b.w + c.w + d.w, 0.0f);
    *(uint2*)&out[(size_t)idx * 4] = *(uint2*)r;
}

__global__ void kan_wprep(const float* __restrict__ bw, const float* __restrict__ sw,
                          const float* __restrict__ ss, __bf16* __restrict__ out) {
    int base = blockIdx.x * 256;
    int idx = base + threadIdx.x;
    float b  = bw[idx];
    float sc = ss[idx];
    const float4* sv = (const float4*)(sw + (size_t)idx * 8);
    float4 a = sv[0], c = sv[1];
    __bf16 r[9];
    r[0] = (__bf16)b;
    r[1] = (__bf16)(a.x * sc); r[2] = (__bf16)(a.y * sc);
    r[3] = (__bf16)(a.z * sc); r[4] = (__bf16)(a.w * sc);
    r[5] = (__bf16)(c.x * sc); r[6] = (__bf16)(c.y * sc);
    r[7] = (__bf16)(c.z * sc); r[8] = (__bf16)(c.w * sc);
    coalesced_store9(out + (size_t)base * 9, r);
}

__global__ void f2bf(const float* __restrict__ in, __bf16* __restrict__ out,
                     int total) {
    int idx = blockIdx.x * 256 + threadIdx.x;
    if (idx < total) out[idx] = (__bf16)in[idx];
}

// --------------------------- staging helper --------------------------------
__device__ __forceinline__ void gload_lds16(const void* g, void* l) {
    __builtin_amdgcn_global_load_lds(
        (const __attribute__((address_space(1))) uint32_t*)g,
        (__attribute__((address_space(3))) uint32_t*)l, 16, 0, 0);
}

// ----------------- big-tile MFMA GEMM: 256x128, wave 64x128 ----------------
// C(M,N) = A(M,K) @ W(N,K)^T, bf16 in, fp32 out (split-K partial per z).
// 256 threads = 4 waves; wave w computes rows [w*64, w*64+64) x all 128 n.
// Per K32-step: 128 MFMA vs 48 ds_read_b128 + 24 KB staging.
// XCD swizzle: each XCD owns a contiguous m-slab. gridDim.y % 8 == 0.
__global__ __launch_bounds__(256, 2) void gemm_big(
    const __bf16* __restrict__ A, const __bf16* __restrict__ W,
    float* __restrict__ Cout, int M, int N, int K, int Ks) {
    constexpr int BK = 32;                    // 64 B LDS rows
    __shared__ __bf16 As[2][256 * BK];        // 2 x 16 KB
    __shared__ __bf16 Ws[2][128 * BK];        // 2 x 8 KB

    const int tid  = threadIdx.x;
    const int lane = tid & 63;
    const int wave = tid >> 6;

    // XCD-aware swizzle (round-robin dispatch: id&7 = XCD)
    const int id    = (blockIdx.z * gridDim.y + blockIdx.y) * gridDim.x + blockIdx.x;
    const int mslab = gridDim.y >> 3;
    const int xcd   = id & 7;
    const int local = id >> 3;
    const int m_off = local % mslab;
    const int rest  = local / mslab;
    const int ntile = rest % gridDim.x;
    const int zt    = rest / gridDim.x;
    const int bm    = (xcd * mslab + m_off) * 256;
    const int bn    = ntile * 128;
    const int kbase = zt * Ks;

    const int wm = wave * 64;
    const int lr = lane & 15;
    const int ks = (lane >> 4) * 8;

    floatx4 acc[4][8] = {};

    auto stage = [&](int buf, int kpos) {
#pragma unroll
        for (int i = 0; i < 4; ++i) {          // A: 1024 chunks of 16 B
            int c = i * 256 + tid;
            int r = c >> 2;
            int s = (c & 3) * 8;
            gload_lds16(&A[(size_t)(bm + r) * K + kbase + kpos + s],
                        &As[buf][(size_t)(i * 256 + wave * 64) * 8]);
        }
#pragma unroll
        for (int i = 0; i < 2; ++i) {          // W: 512 chunks
            int c = i * 256 + tid;
            int r = c >> 2;
            int s = (c & 3) * 8;
            gload_lds16(&W[(size_t)(bn + r) * K + kbase + kpos + s],
                        &Ws[buf][(size_t)(i * 256 + wave * 64) * 8]);
        }
    };

    auto compute = [&](int buf) {
        bf16x8 af[4], wf[8];
#pragma unroll
        for (int t = 0; t < 4; ++t)
            af[t] = *(const bf16x8*)&As[buf][(wm + t * 16 + lr) * BK + ks];
#pragma unroll
        for (int t = 0; t < 8; ++t)
            wf[t] = *(const bf16x8*)&Ws[buf][(t * 16 + lr) * BK + ks];
#pragma unroll
        for (int mt = 0; mt < 4; ++mt)
#pragma unroll
            for (int nt = 0; nt < 8; ++nt)
                acc[mt][nt] = __builtin_amdgcn_mfma_f32_16x16x32_bf16(
                    af[mt], wf[nt], acc[mt][nt], 0, 0, 0);
    };

    stage(0, 0);
    for (int k0 = 0; k0 < Ks; k0 += 2 * BK) {
        __syncthreads();
        if (k0 + BK < Ks) stage(1, k0 + BK);
        compute(0);
        __syncthreads();
        if (k0 + 2 * BK < Ks) stage(0, k0 + 2 * BK);
        compute(1);
    }

    // C/D layout: col = lane&15, row = (lane>>4)*4 + reg
    float* Cz = Cout + (size_t)zt * M * N;
    const int col = lane & 15;
    const int rquad = (lane >> 4) * 4;
#pragma unroll
    for (int mt = 0; mt < 4; ++mt) {
#pragma unroll
        for (int nt = 0; nt < 8; ++nt) {
            int n = bn + nt * 16 + col;
#pragma unroll
            for (int rg = 0; rg < 4; ++rg) {
                int m = bm + wm + mt * 16 + rquad + rg;
                Cz[(size_t)m * N + n] = acc[mt][nt][rg];
            }
        }
    }
}

// ----------------- 128x128 MFMA GEMM (dense epilogue) ----------------------
__global__ __launch_bounds__(256) void gemm_dense(
    const __bf16* __restrict__ A, const __bf16* __restrict__ W,
    float* __restrict__ Cout, const float* __restrict__ bias,
    int M, int N, int K) {
    constexpr int BK = 32;
    __shared__ __bf16 As[2][128 * BK];
    __shared__ __bf16 Ws[2][128 * BK];

    const int tid  = threadIdx.x;
    const int lane = tid & 63;
    const int wave = tid >> 6;

    const int id    = blockIdx.y * gridDim.x + blockIdx.x;
    const int mslab = gridDim.y >> 3;
    const int xcd   = id & 7;
    const int local = id >> 3;
    const int m_off = local % mslab;
    const int ntile = local / mslab;
    const int bm    = (xcd * mslab + m_off) * 128;
    const int bn    = ntile * 128;

    const int wm = (wave >> 1) * 64;
    const int wn = (wave & 1) * 64;
    const int lr = lane & 15;
    const int ks = (lane >> 4) * 8;

    floatx4 acc[4][4] = {};

    auto stage = [&](int buf, int kpos) {
#pragma unroll
        for (int i = 0; i < 2; ++i) {
            int c = i * 256 + tid;
            int r = c >> 2;
            int s = (c & 3) * 8;
            gload_lds16(&A[(size_t)(bm + r) * K + kpos + s],
                        &As[buf][(size_t)(i * 256 + wave * 64) * 8]);
            gload_lds16(&W[(size_t)(bn + r) * K + kpos + s],
                        &Ws[buf][(size_t)(i * 256 + wave * 64) * 8]);
        }
    };

    auto compute = [&](int buf) {
        bf16x8 af[4], wf[4];
#pragma unroll
        for (int t = 0; t < 4; ++t) {
            af[t] = *(const bf16x8*)&As[buf][(wm + t * 16 + lr) * BK + ks];
            wf[t] = *(const bf16x8*)&Ws[buf][(wn + t * 16 + lr) * BK + ks];
        }
#pragma unroll
        for (int mt = 0; mt < 4; ++mt)
#pragma unroll
            for (int nt = 0; nt < 4; ++nt)
                acc[mt][nt] = __builtin_amdgcn_mfma_f32_16x16x32_bf16(
                    af[mt], wf[nt], acc[mt][nt], 0, 0, 0);
    };

    stage(0, 0);
    for (int k0 = 0; k0 < K; k0 += 2 * BK) {
        __syncthreads();
        if (k0 + BK < K) stage(1, k0 + BK);
        compute(0);
        __syncthreads();
        if (k0 + 2 * BK < K) stage(0, k0 + 2 * BK);
        compute(1);
    }

    const int col = lane & 15;
    const int rquad = (lane >> 4) * 4;
#pragma unroll
    for (int mt = 0; mt < 4; ++mt) {
#pragma unroll
        for (int nt = 0; nt < 4; ++nt) {
            int n = bn + wn + nt * 16 + col;
#pragma unroll
            for (int rg = 0; rg < 4; ++rg) {
                int m = bm + wm + mt * 16 + rquad + rg;
                Cout[(size_t)m * N + n] = acc[mt][nt][rg] + bias[n];
            }
        }
    }
}

// ---------------------------------------------------------------------------
extern "C" void kernel_launch(void* const* d_in, const int* in_sizes, int n_in,
                              void* d_out, int out_size, void* d_ws, size_t ws_size,
                              hipStream_t stream) {
    const float* x   = (const float*)d_in[0];
    const float* bw0 = (const float*)d_in[1];
    const float* sw0 = (const float*)d_in[2];
    const float* ss0 = (const float*)d_in[3];
    const float* bw1 = (const float*)d_in[4];
    const float* sw1 = (const float*)d_in[5];
    const float* ss1 = (const float*)d_in[6];
    const float* dw  = (const float*)d_in[7];
    const float* db  = (const float*)d_in[8];
    float* out = (float*)d_out;

    char* ws = (char*)d_ws;
    __bf16* A0  = (__bf16*)(ws + OFF_A0);
    __bf16* W0  = (__bf16*)(ws + OFF_W0);
    __bf16* A1  = (__bf16*)(ws + OFF_A1);
    float*  P0  = (float*)(ws + OFF_P0);
    __bf16* W1  = (__bf16*)(ws + OFF_W1);
    float*  P1  = (float*)(ws + OFF_P1);
    __bf16* h1r = (__bf16*)(ws + OFF_H1R);
    __bf16* dwb = (__bf16*)(ws + OFF_DW);

    // Layer 0: K = 9216, splitK=2 -> grid 16x16x2 = 512 blocks (2/CU)
    kan_wprep<<<(H0N * DIN) / 256, 256, 0, stream>>>(bw0, sw0, ss0, W0);
    kan_act<<<(BATCH * DIN) / 256, 256, 0, stream>>>(x, A0);
    gemm_big<<<dim3(H0N / 128, BATCH / 256, 2), 256, 0, stream>>>(
        A0, W0, P0, BATCH, H0N, DIN * 9, DIN * 9 / 2);

    // Layer 1: K = 18432, splitK=4 -> grid 8x16x4 = 512 blocks (2/CU)
    kan_wprep<<<(H1N * H0N) / 256, 256, 0, stream>>>(bw1, sw1, ss1, W1);
    kan_act_sum2<<<(BATCH * H0N) / 256, 256, 0, stream>>>(
        P0, P0 + (size_t)BATCH * H0N, A1);
    gemm_big<<<dim3(H1N / 128, BATCH / 256, 4), 256, 0, stream>>>(
        A1, W1, P1, BATCH, H1N, H0N * 9, H0N * 9 / 4);

    // relu(sum of 4 partials) -> bf16
    relu_sum4<<<(BATCH * H1N / 4) / 256, 256, 0, stream>>>(
        P1, (size_t)BATCH * H1N, h1r, BATCH * H1N / 4);

    // Dense: out = h1r @ dw^T + db  (K = 1024)
    f2bf<<<(LOUT * H1N) / 256, 256, 0, stream>>>(dw, dwb, LOUT * H1N);
    gemm_dense<<<dim3(LOUT / 128, BATCH / 128), 256, 0, stream>>>(
        h1r, dwb, out, db, BATCH, LOUT, H1N);
}